// Round 4
// baseline (545.605 us; speedup 1.0000x reference)
//
#include <hip/hip_runtime.h>

// ---------------------------------------------------------------------------
// ResNet sparse-conv block, round 4: 64-row tiles (2x blocks in flight),
// vmcnt-aware issue order (B(k+1) then A(k+1), both double-buffered).
//   memset      : zero stats
//   prep2       : blocks<54: coalesced W->bf16 fragment pack; rest: stats of x
//   bn_relu_f32 : h1 = bf16(relu(bn1(x)))
//   spconv      : out1(bf16) = sum_k gather(h1) @ W1[k], fused stats
//   bn_relu_b16 : h2 = bf16(relu(bn2(out1)))
//   spconv      : out(fp32) = sum_k gather(h2) @ W2[k] + x
// ---------------------------------------------------------------------------

#define KOFF 27

typedef __bf16 bf16x8 __attribute__((ext_vector_type(8)));
typedef float floatx4 __attribute__((ext_vector_type(4)));

__device__ __forceinline__ unsigned short f2bf(float x) {
    union { float f; unsigned int u; } v; v.f = x;
    unsigned int u = v.u;
    unsigned int r = u + 0x7FFFu + ((u >> 16) & 1u);
    return (unsigned short)(r >> 16);
}
__device__ __forceinline__ float bf2f(unsigned short s) {
    union { float f; unsigned int u; } v; v.u = ((unsigned int)s) << 16; return v.f;
}

// --- prep: blocks 0..53 pack W (coalesced, LDS transpose); rest: x stats ----
// frag element j of (ct,ks) for lane (q,l15) = W[k][cin=ks*32+q*8+j][cout=ct*16+l15]
__global__ void prep2(const float* __restrict__ W1, const float* __restrict__ W2,
                      unsigned short* __restrict__ W1f, unsigned short* __restrict__ W2f,
                      const float* __restrict__ x, float* __restrict__ stats,
                      int total) {
    int b = blockIdx.x, t = threadIdx.x;
    if (b < 54) {
        __shared__ float sW[64 * 68];
        int k = b % 27;
        const float* src = (b < 27 ? W1 : W2) + k * 4096;
        unsigned short* dst = (b < 27 ? W1f : W2f) + (size_t)k * 4096;
        #pragma unroll
        for (int i = 0; i < 4; ++i) {                 // 1024 float4 = 4096 floats
            int i4 = t + i * 256;
            float4 v = ((const float4*)src)[i4];
            int f = i4 * 4, r = f >> 6, c = f & 63;
            sW[r * 68 + c]     = v.x;
            sW[r * 68 + c + 1] = v.y;
            sW[r * 68 + c + 2] = v.z;
            sW[r * 68 + c + 3] = v.w;
        }
        __syncthreads();
        int fi = (t >> 5) & 7, ct = fi >> 1, ks = fi & 1;
        unsigned short o[16];
        #pragma unroll
        for (int d = 0; d < 2; ++d) {
            int lane2 = (t * 2 + d) & 63, q = lane2 >> 4, l15 = lane2 & 15;
            #pragma unroll
            for (int j = 0; j < 8; ++j) {
                int cin = ks * 32 + q * 8 + j, cout = ct * 16 + l15;
                o[d * 8 + j] = f2bf(sW[cin * 68 + cout]);
            }
        }
        ((uint4*)(dst + t * 16))[0] = *(const uint4*)(o);
        ((uint4*)(dst + t * 16))[1] = *(const uint4*)(o + 8);
        return;
    }
    __shared__ float s[128];
    if (t < 128) s[t] = 0.f;
    __syncthreads();
    int i = (b - 54) * 256 + t;
    int stride = (gridDim.x - 54) * 256;              // multiple of 64
    int c = i & 63;
    float s1 = 0.f, s2 = 0.f;
    for (; i < total; i += stride) { float v = x[i]; s1 += v; s2 += v * v; }
    atomicAdd(&s[c], s1);
    atomicAdd(&s[64 + c], s2);
    __syncthreads();
    if (t < 64) { atomicAdd(&stats[t], s[t]); atomicAdd(&stats[64 + t], s[64 + t]); }
}

// --- BN + ReLU + bf16 cast, fp32 input --------------------------------------
__global__ void bn_relu_f32(const float* __restrict__ in, const float* __restrict__ sums,
                            const float* __restrict__ gamma, const float* __restrict__ beta,
                            unsigned short* __restrict__ out, int total4, float invN) {
    __shared__ float sab[128];
    int t = threadIdx.x;
    if (t < 64) {
        float mu  = sums[t] * invN;
        float var = fmaxf(sums[64 + t] * invN - mu * mu, 0.f);
        float a   = gamma[t] * rsqrtf(var + 1e-5f);
        sab[t] = a; sab[64 + t] = beta[t] - mu * a;
    }
    __syncthreads();
    int i = blockIdx.x * blockDim.x + t;
    int stride = gridDim.x * blockDim.x;
    for (; i < total4; i += stride) {
        float4 v = ((const float4*)in)[i];
        int c0 = (i << 2) & 63;
        ushort4 o;
        o.x = f2bf(fmaxf(sab[c0]     * v.x + sab[64 + c0],     0.f));
        o.y = f2bf(fmaxf(sab[c0 + 1] * v.y + sab[64 + c0 + 1], 0.f));
        o.z = f2bf(fmaxf(sab[c0 + 2] * v.z + sab[64 + c0 + 2], 0.f));
        o.w = f2bf(fmaxf(sab[c0 + 3] * v.w + sab[64 + c0 + 3], 0.f));
        ((ushort4*)out)[i] = o;
    }
}

// --- BN + ReLU + bf16 cast, bf16 input --------------------------------------
__global__ void bn_relu_b16(const unsigned short* __restrict__ in, const float* __restrict__ sums,
                            const float* __restrict__ gamma, const float* __restrict__ beta,
                            unsigned short* __restrict__ out, int total8, float invN) {
    __shared__ float sab[128];
    int t = threadIdx.x;
    if (t < 64) {
        float mu  = sums[t] * invN;
        float var = fmaxf(sums[64 + t] * invN - mu * mu, 0.f);
        float a   = gamma[t] * rsqrtf(var + 1e-5f);
        sab[t] = a; sab[64 + t] = beta[t] - mu * a;
    }
    __syncthreads();
    int i = blockIdx.x * blockDim.x + t;
    int stride = gridDim.x * blockDim.x;
    for (; i < total8; i += stride) {
        uint4 v = ((const uint4*)in)[i];
        int c0 = (i << 3) & 63;
        unsigned int w[4] = {v.x, v.y, v.z, v.w};
        unsigned int o[4];
        #pragma unroll
        for (int p = 0; p < 4; ++p) {
            float f0 = bf2f((unsigned short)(w[p] & 0xffff));
            float f1 = bf2f((unsigned short)(w[p] >> 16));
            int c = c0 + p * 2;
            unsigned short r0 = f2bf(fmaxf(sab[c]     * f0 + sab[64 + c],     0.f));
            unsigned short r1 = f2bf(fmaxf(sab[c + 1] * f1 + sab[64 + c + 1], 0.f));
            o[p] = (unsigned int)r0 | ((unsigned int)r1 << 16);
        }
        ((uint4*)out)[i] = make_uint4(o[0], o[1], o[2], o[3]);
    }
}

#define MFMA(a, b, c) __builtin_amdgcn_mfma_f32_16x16x32_bf16(a, b, c, 0, 0, 0)

// --- 64-row-tile gather->register MFMA sparse conv --------------------------
// 4 waves/block, wave owns ONE 16-row m-tile -> 2x the blocks/waves in flight
// vs round 3. Issue order per iter k (vmcnt is in-order!):
//   B(k+1) loads -> A(k+1) gathers -> idx(k+2) -> MFMAs(k)
// MFMA(k) consumes B(k)/A(k) issued a full iteration earlier; the s_waitcnt
// before MFMAs leaves all (k+1) loads outstanding. Regs ~116 < 128 @ (256,4).
__global__ __launch_bounds__(256, 4) void spconv(
        const unsigned short* __restrict__ h,     // [N,64] bf16
        const int* __restrict__ idx,              // [N,27]
        const unsigned short* __restrict__ Wf,    // packed frags [27][8][64][8]
        unsigned short* __restrict__ outb,        // conv1 out (bf16) or null
        float* __restrict__ outf,                 // conv2 out (fp32) or null
        const float* __restrict__ resid,          // conv2 residual or null
        float* __restrict__ stats,                // conv1 fused stats or null
        int N) {
    __shared__ float sE[64 * 68];
    __shared__ float sred[128];
    int t = threadIdx.x, lane = t & 63, wid = t >> 6;
    int q = lane >> 4, l15 = lane & 15;
    int base = blockIdx.x * 64;
    if (t < 128) sred[t] = 0.f;
    __syncthreads();

    int r0 = base + wid * 16 + l15;
    const int* ip = idx + (size_t)min(r0, N - 1) * KOFF;
    int qo = q * 8;

    floatx4 acc[4];
    #pragma unroll
    for (int ct = 0; ct < 4; ++ct) acc[ct] = floatx4{0.f, 0.f, 0.f, 0.f};

    // prologue: B(0), A(0), idx(1)
    bf16x8 B0[8], B1[8];
    {
        const unsigned short* wp = Wf + (size_t)lane * 8;
        #pragma unroll
        for (int i = 0; i < 8; ++i) B0[i] = *(const bf16x8*)(wp + i * 512);
    }
    int g = ip[0];
    const unsigned short* hp0 = h + ((size_t)g << 6) + qo;
    bf16x8 Aa = *(const bf16x8*)hp0;
    bf16x8 Ab = *(const bf16x8*)(hp0 + 32);
    int gn = ip[1];
    bf16x8 Na, Nb;

#define BODY(BC, BN, KK) {                                                     \
    if ((KK) < KOFF - 1) {                                                     \
        const unsigned short* wq = Wf + (size_t)((KK) + 1) * 4096 + (size_t)lane * 8; \
        _Pragma("unroll")                                                      \
        for (int i = 0; i < 8; ++i) BN[i] = *(const bf16x8*)(wq + i * 512);    \
        const unsigned short* hp = h + ((size_t)gn << 6) + qo;                 \
        Na = *(const bf16x8*)hp;                                               \
        Nb = *(const bf16x8*)(hp + 32);                                        \
    }                                                                          \
    if ((KK) < KOFF - 2) gn = ip[(KK) + 2];                                    \
    acc[0] = MFMA(Aa, BC[0], acc[0]); acc[0] = MFMA(Ab, BC[1], acc[0]);        \
    acc[1] = MFMA(Aa, BC[2], acc[1]); acc[1] = MFMA(Ab, BC[3], acc[1]);        \
    acc[2] = MFMA(Aa, BC[4], acc[2]); acc[2] = MFMA(Ab, BC[5], acc[2]);        \
    acc[3] = MFMA(Aa, BC[6], acc[3]); acc[3] = MFMA(Ab, BC[7], acc[3]);        \
    Aa = Na; Ab = Nb;                                                          \
}

    #pragma unroll 1
    for (int kk = 0; kk < KOFF - 1; kk += 2) {
        BODY(B0, B1, kk)
        BODY(B1, B0, kk + 1)
    }
    BODY(B0, B1, KOFF - 1)      // k = 26, current buffer is B0, no prefetch
#undef BODY

    // fused per-channel stats of conv1 output (tail rows masked)
    if (stats) {
        #pragma unroll
        for (int ct = 0; ct < 4; ++ct) {
            float s1 = 0.f, s2 = 0.f;
            #pragma unroll
            for (int r = 0; r < 4; ++r) {
                int rowc = base + wid * 16 + q * 4 + r;
                float vv = (rowc < N) ? acc[ct][r] : 0.f;
                s1 += vv; s2 += vv * vv;
            }
            s1 += __shfl_xor(s1, 16); s2 += __shfl_xor(s2, 16);
            s1 += __shfl_xor(s1, 32); s2 += __shfl_xor(s2, 32);
            if (q == 0) {
                atomicAdd(&sred[ct * 16 + l15], s1);
                atomicAdd(&sred[64 + ct * 16 + l15], s2);
            }
        }
    }

    // epilogue: transpose through LDS -> coalesced stores
    #pragma unroll
    for (int ct = 0; ct < 4; ++ct)
        #pragma unroll
        for (int r = 0; r < 4; ++r)
            sE[(wid * 16 + q * 4 + r) * 68 + ct * 16 + l15] = acc[ct][r];
    __syncthreads();
    if (stats && t < 64) {
        atomicAdd(&stats[t], sred[t]);
        atomicAdd(&stats[64 + t], sred[64 + t]);
    }

    int rr = t >> 2, cc = t & 3;
    int grow = base + rr;
    if (grow < N) {
        const float* sp = sE + rr * 68 + cc * 16;
        if (outb) {
            unsigned short o[16];
            #pragma unroll
            for (int j = 0; j < 16; ++j) o[j] = f2bf(sp[j]);
            unsigned short* op = outb + ((size_t)grow << 6) + cc * 16;
            ((uint4*)op)[0] = *(const uint4*)(o);
            ((uint4*)op)[1] = *(const uint4*)(o + 8);
        } else {
            const float* rp = resid + ((size_t)grow << 6) + cc * 16;
            float* op = outf + ((size_t)grow << 6) + cc * 16;
            #pragma unroll
            for (int j = 0; j < 4; ++j) {
                float4 v = *(const float4*)(sp + j * 4);
                float4 rv = *(const float4*)(rp + j * 4);
                v.x += rv.x; v.y += rv.y; v.z += rv.z; v.w += rv.w;
                *(float4*)(op + j * 4) = v;
            }
        }
    }
}

// ---------------------------------------------------------------------------
extern "C" void kernel_launch(void* const* d_in, const int* in_sizes, int n_in,
                              void* d_out, int out_size, void* d_ws, size_t ws_size,
                              hipStream_t stream) {
    const float* x      = (const float*)d_in[0];
    const int*   nbr    = (const int*)  d_in[1];
    const float* W1     = (const float*)d_in[2];
    const float* gamma1 = (const float*)d_in[3];
    const float* beta1  = (const float*)d_in[4];
    const float* W2     = (const float*)d_in[5];
    const float* gamma2 = (const float*)d_in[6];
    const float* beta2  = (const float*)d_in[7];
    float* out = (float*)d_out;

    int N = in_sizes[0] / 64;
    float invN = 1.0f / (float)N;

    char* ws = (char*)d_ws;
    float*          stats = (float*)ws;                           // 512 floats
    unsigned short* W1f   = (unsigned short*)(ws + 4096);         // 110592 bf16
    unsigned short* W2f   = W1f + 110592;
    unsigned short* hbuf  = W2f + 110592;                         // [N,64] bf16
    unsigned short* out1b = hbuf + (size_t)N * 64;                // [N,64] bf16

    int nb = (N + 63) / 64;

    hipMemsetAsync(stats, 0, 2048, stream);
    prep2<<<54 + 512, 256, 0, stream>>>(W1, W2, W1f, W2f, x, stats, N * 64);
    bn_relu_f32<<<768, 256, 0, stream>>>(x, stats, gamma1, beta1, hbuf, N * 16, invN);
    spconv<<<nb, 256, 0, stream>>>(hbuf, nbr, W1f, out1b, nullptr, nullptr, stats + 256, N);
    bn_relu_b16<<<768, 256, 0, stream>>>(out1b, stats + 256, gamma2, beta2, hbuf, N * 8, invN);
    spconv<<<nb, 256, 0, stream>>>(hbuf, nbr, W2f, nullptr, out, x, nullptr, N);
}

// Round 5
// 425.265 us; speedup vs baseline: 1.2830x; 1.2830x over previous
//
#include <hip/hip_runtime.h>

// ---------------------------------------------------------------------------
// ResNet sparse-conv block, round 5: 128-row blocks, LDS-shared double-buffered
// B (loads the 8KB W-set once per block per k instead of once per wave),
// depth-2 register-pipelined A gathers, raw s_barrier (no vmcnt(0) drain).
// ---------------------------------------------------------------------------

#define KOFF 27

typedef __bf16 bf16x8 __attribute__((ext_vector_type(8)));
typedef float floatx4 __attribute__((ext_vector_type(4)));

__device__ __forceinline__ unsigned short f2bf(float x) {
    union { float f; unsigned int u; } v; v.f = x;
    unsigned int u = v.u;
    unsigned int r = u + 0x7FFFu + ((u >> 16) & 1u);
    return (unsigned short)(r >> 16);
}
__device__ __forceinline__ float bf2f(unsigned short s) {
    union { float f; unsigned int u; } v; v.u = ((unsigned int)s) << 16; return v.f;
}

// --- prep: blocks 0..53 pack W (coalesced, LDS transpose); rest: x stats ----
// frag element j of (ct,ks) for lane (q,l15) = W[k][cin=ks*32+q*8+j][cout=ct*16+l15]
__global__ void prep2(const float* __restrict__ W1, const float* __restrict__ W2,
                      unsigned short* __restrict__ W1f, unsigned short* __restrict__ W2f,
                      const float* __restrict__ x, float* __restrict__ stats,
                      int total) {
    int b = blockIdx.x, t = threadIdx.x;
    if (b < 54) {
        __shared__ float sW[64 * 68];
        int k = b % 27;
        const float* src = (b < 27 ? W1 : W2) + k * 4096;
        unsigned short* dst = (b < 27 ? W1f : W2f) + (size_t)k * 4096;
        #pragma unroll
        for (int i = 0; i < 4; ++i) {
            int i4 = t + i * 256;
            float4 v = ((const float4*)src)[i4];
            int f = i4 * 4, r = f >> 6, c = f & 63;
            sW[r * 68 + c]     = v.x;
            sW[r * 68 + c + 1] = v.y;
            sW[r * 68 + c + 2] = v.z;
            sW[r * 68 + c + 3] = v.w;
        }
        __syncthreads();
        int fi = (t >> 5) & 7, ct = fi >> 1, ks = fi & 1;
        unsigned short o[16];
        #pragma unroll
        for (int d = 0; d < 2; ++d) {
            int lane2 = (t * 2 + d) & 63, q = lane2 >> 4, l15 = lane2 & 15;
            #pragma unroll
            for (int j = 0; j < 8; ++j) {
                int cin = ks * 32 + q * 8 + j, cout = ct * 16 + l15;
                o[d * 8 + j] = f2bf(sW[cin * 68 + cout]);
            }
        }
        ((uint4*)(dst + t * 16))[0] = *(const uint4*)(o);
        ((uint4*)(dst + t * 16))[1] = *(const uint4*)(o + 8);
        return;
    }
    __shared__ float s[128];
    if (t < 128) s[t] = 0.f;
    __syncthreads();
    int i = (b - 54) * 256 + t;
    int stride = (gridDim.x - 54) * 256;
    int c = i & 63;
    float s1 = 0.f, s2 = 0.f;
    for (; i < total; i += stride) { float v = x[i]; s1 += v; s2 += v * v; }
    atomicAdd(&s[c], s1);
    atomicAdd(&s[64 + c], s2);
    __syncthreads();
    if (t < 64) { atomicAdd(&stats[t], s[t]); atomicAdd(&stats[64 + t], s[64 + t]); }
}

// --- BN + ReLU + bf16 cast, fp32 input --------------------------------------
__global__ void bn_relu_f32(const float* __restrict__ in, const float* __restrict__ sums,
                            const float* __restrict__ gamma, const float* __restrict__ beta,
                            unsigned short* __restrict__ out, int total4, float invN) {
    __shared__ float sab[128];
    int t = threadIdx.x;
    if (t < 64) {
        float mu  = sums[t] * invN;
        float var = fmaxf(sums[64 + t] * invN - mu * mu, 0.f);
        float a   = gamma[t] * rsqrtf(var + 1e-5f);
        sab[t] = a; sab[64 + t] = beta[t] - mu * a;
    }
    __syncthreads();
    int i = blockIdx.x * blockDim.x + t;
    int stride = gridDim.x * blockDim.x;
    for (; i < total4; i += stride) {
        float4 v = ((const float4*)in)[i];
        int c0 = (i << 2) & 63;
        ushort4 o;
        o.x = f2bf(fmaxf(sab[c0]     * v.x + sab[64 + c0],     0.f));
        o.y = f2bf(fmaxf(sab[c0 + 1] * v.y + sab[64 + c0 + 1], 0.f));
        o.z = f2bf(fmaxf(sab[c0 + 2] * v.z + sab[64 + c0 + 2], 0.f));
        o.w = f2bf(fmaxf(sab[c0 + 3] * v.w + sab[64 + c0 + 3], 0.f));
        ((ushort4*)out)[i] = o;
    }
}

// --- BN + ReLU + bf16 cast, bf16 input --------------------------------------
__global__ void bn_relu_b16(const unsigned short* __restrict__ in, const float* __restrict__ sums,
                            const float* __restrict__ gamma, const float* __restrict__ beta,
                            unsigned short* __restrict__ out, int total8, float invN) {
    __shared__ float sab[128];
    int t = threadIdx.x;
    if (t < 64) {
        float mu  = sums[t] * invN;
        float var = fmaxf(sums[64 + t] * invN - mu * mu, 0.f);
        float a   = gamma[t] * rsqrtf(var + 1e-5f);
        sab[t] = a; sab[64 + t] = beta[t] - mu * a;
    }
    __syncthreads();
    int i = blockIdx.x * blockDim.x + t;
    int stride = gridDim.x * blockDim.x;
    for (; i < total8; i += stride) {
        uint4 v = ((const uint4*)in)[i];
        int c0 = (i << 3) & 63;
        unsigned int w[4] = {v.x, v.y, v.z, v.w};
        unsigned int o[4];
        #pragma unroll
        for (int p = 0; p < 4; ++p) {
            float f0 = bf2f((unsigned short)(w[p] & 0xffff));
            float f1 = bf2f((unsigned short)(w[p] >> 16));
            int c = c0 + p * 2;
            unsigned short r0 = f2bf(fmaxf(sab[c]     * f0 + sab[64 + c],     0.f));
            unsigned short r1 = f2bf(fmaxf(sab[c + 1] * f1 + sab[64 + c + 1], 0.f));
            o[p] = (unsigned int)r0 | ((unsigned int)r1 << 16);
        }
        ((uint4*)out)[i] = make_uint4(o[0], o[1], o[2], o[3]);
    }
}

#define MFMA(a, b, c) __builtin_amdgcn_mfma_f32_16x16x32_bf16(a, b, c, 0, 0, 0)
// lgkmcnt(0), vmcnt=no-wait(63), expcnt=no-wait(7):  [15:14]=3,[11:8]=0,[6:4]=7,[3:0]=0xF
#define WAIT_LGKM0() __builtin_amdgcn_s_waitcnt(0xC07F)

// --- LDS-shared-B gather->register MFMA sparse conv -------------------------
// Block 256 thr (4 waves), 128 output rows; wave owns two 16-row m-tiles.
// Per k: the block stages the 8KB B-set ONCE (each wave a 2KB quarter ->
// ds_write into sB[k&1]); A-frags gathered from global 2 iters ahead into a
// 3-deep register buffer. Raw s_barrier + manual lgkmcnt(0) only; all vmcnt
// waits left to the compiler's minimal dependence-based insertion so A/B
// prefetch loads stay outstanding across the barrier.
__global__ __launch_bounds__(256, 4) void spconv(
        const unsigned short* __restrict__ h,     // [N,64] bf16
        const int* __restrict__ idx,              // [N,27]
        const unsigned short* __restrict__ Wf,    // packed frags [27][8][64][8]
        unsigned short* __restrict__ outb,        // conv1 out (bf16) or null
        float* __restrict__ outf,                 // conv2 out (fp32) or null
        const float* __restrict__ resid,          // conv2 residual or null
        float* __restrict__ stats,                // conv1 fused stats or null
        int N) {
    __shared__ unsigned short sB[2][4096];        // double-buffered B (8KB each)
    __shared__ float sE[128 * 68];                // epilogue transpose
    __shared__ float sred[128];
    int t = threadIdx.x, lane = t & 63, wid = t >> 6;
    int q = lane >> 4, l15 = lane & 15;
    int base = blockIdx.x * 128;
    if (t < 128) sred[t] = 0.f;

    int r0 = base + wid * 32 + l15;
    int r1 = r0 + 16;
    const int* ip0 = idx + (size_t)min(r0, N - 1) * KOFF;
    const int* ip1 = idx + (size_t)min(r1, N - 1) * KOFF;
    int qo = q * 8;

    floatx4 acc[2][4];
    #pragma unroll
    for (int a_ = 0; a_ < 2; ++a_)
        #pragma unroll
        for (int b_ = 0; b_ < 4; ++b_)
            acc[a_][b_] = floatx4{0.f, 0.f, 0.f, 0.f};

    // ---- prologue: A(0), A(1) gathers; B(0) staged+written; B(1) staged ----
    bf16x8 A0[4], A1[4], A2[4];
    {
        int g0 = ip0[0], g1 = ip1[0];
        const unsigned short* p0 = h + ((size_t)g0 << 6) + qo;
        const unsigned short* p1 = h + ((size_t)g1 << 6) + qo;
        A0[0] = *(const bf16x8*)p0; A0[1] = *(const bf16x8*)(p0 + 32);
        A0[2] = *(const bf16x8*)p1; A0[3] = *(const bf16x8*)(p1 + 32);
        g0 = ip0[1]; g1 = ip1[1];
        p0 = h + ((size_t)g0 << 6) + qo;
        p1 = h + ((size_t)g1 << 6) + qo;
        A1[0] = *(const bf16x8*)p0; A1[1] = *(const bf16x8*)(p0 + 32);
        A1[2] = *(const bf16x8*)p1; A1[3] = *(const bf16x8*)(p1 + 32);
    }
    int gc0 = ip0[2], gc1 = ip1[2];

    const uint4* Wf4 = (const uint4*)Wf;          // 8 shorts per uint4
    int bo = wid * 128 + lane * 2;                // this thread's B quarter slot
    uint4 bs0 = Wf4[bo], bs1 = Wf4[bo + 1];       // B(0)
    ((uint4*)sB[0])[bo] = bs0; ((uint4*)sB[0])[bo + 1] = bs1;
    bs0 = Wf4[512 + bo]; bs1 = Wf4[512 + bo + 1]; // B(1) staged in regs

#define COMPUTE(ACUR, CB) {                                                    \
    const bf16x8* bp = (const bf16x8*)sB[CB];                                  \
    bf16x8 f0 = bp[lane], f1 = bp[64 + lane], f2 = bp[128 + lane], f3 = bp[192 + lane]; \
    acc[0][0] = MFMA(ACUR[0], f0, acc[0][0]); acc[0][0] = MFMA(ACUR[1], f1, acc[0][0]); \
    acc[0][1] = MFMA(ACUR[0], f2, acc[0][1]); acc[0][1] = MFMA(ACUR[1], f3, acc[0][1]); \
    acc[1][0] = MFMA(ACUR[2], f0, acc[1][0]); acc[1][0] = MFMA(ACUR[3], f1, acc[1][0]); \
    acc[1][1] = MFMA(ACUR[2], f2, acc[1][1]); acc[1][1] = MFMA(ACUR[3], f3, acc[1][1]); \
    f0 = bp[256 + lane]; f1 = bp[320 + lane]; f2 = bp[384 + lane]; f3 = bp[448 + lane]; \
    acc[0][2] = MFMA(ACUR[0], f0, acc[0][2]); acc[0][2] = MFMA(ACUR[1], f1, acc[0][2]); \
    acc[0][3] = MFMA(ACUR[0], f2, acc[0][3]); acc[0][3] = MFMA(ACUR[1], f3, acc[0][3]); \
    acc[1][2] = MFMA(ACUR[2], f0, acc[1][2]); acc[1][2] = MFMA(ACUR[3], f1, acc[1][2]); \
    acc[1][3] = MFMA(ACUR[2], f2, acc[1][3]); acc[1][3] = MFMA(ACUR[3], f3, acc[1][3]); \
}

// full-rate body for k <= 23: always writes B(k+1), stages B(k+2), gathers A(k+2)
#define BODY_FULL(ACUR, ALD, KRT, CB, NB) {                                    \
    WAIT_LGKM0();                                                              \
    __builtin_amdgcn_s_barrier();                                              \
    ((uint4*)sB[NB])[bo] = bs0; ((uint4*)sB[NB])[bo + 1] = bs1;                \
    bs0 = Wf4[((KRT) + 2) * 512 + bo]; bs1 = Wf4[((KRT) + 2) * 512 + bo + 1];  \
    {                                                                          \
        const unsigned short* p0 = h + ((size_t)gc0 << 6) + qo;                \
        const unsigned short* p1 = h + ((size_t)gc1 << 6) + qo;                \
        ALD[0] = *(const bf16x8*)p0; ALD[1] = *(const bf16x8*)(p0 + 32);       \
        ALD[2] = *(const bf16x8*)p1; ALD[3] = *(const bf16x8*)(p1 + 32);       \
    }                                                                          \
    gc0 = ip0[(KRT) + 3]; gc1 = ip1[(KRT) + 3];                                \
    COMPUTE(ACUR, CB)                                                          \
}

    #pragma unroll 1
    for (int kk = 0; kk < 24; kk += 6) {
        BODY_FULL(A0, A2, kk + 0, 0, 1)
        BODY_FULL(A1, A0, kk + 1, 1, 0)
        BODY_FULL(A2, A1, kk + 2, 0, 1)
        BODY_FULL(A0, A2, kk + 3, 1, 0)
        BODY_FULL(A1, A0, kk + 4, 0, 1)
        BODY_FULL(A2, A1, kk + 5, 1, 0)
    }
    // k = 24: write B(25), stage B(26), gather A(26) (gc holds ip[26])
    {
        WAIT_LGKM0();
        __builtin_amdgcn_s_barrier();
        ((uint4*)sB[1])[bo] = bs0; ((uint4*)sB[1])[bo + 1] = bs1;
        bs0 = Wf4[26 * 512 + bo]; bs1 = Wf4[26 * 512 + bo + 1];
        {
            const unsigned short* p0 = h + ((size_t)gc0 << 6) + qo;
            const unsigned short* p1 = h + ((size_t)gc1 << 6) + qo;
            A2[0] = *(const bf16x8*)p0; A2[1] = *(const bf16x8*)(p0 + 32);
            A2[2] = *(const bf16x8*)p1; A2[3] = *(const bf16x8*)(p1 + 32);
        }
        COMPUTE(A0, 0)
    }
    // k = 25: write B(26)
    {
        WAIT_LGKM0();
        __builtin_amdgcn_s_barrier();
        ((uint4*)sB[0])[bo] = bs0; ((uint4*)sB[0])[bo + 1] = bs1;
        COMPUTE(A1, 1)
    }
    // k = 26
    {
        WAIT_LGKM0();
        __builtin_amdgcn_s_barrier();
        COMPUTE(A2, 0)
    }
#undef BODY_FULL
#undef COMPUTE

    // fused per-channel stats of conv1 output (tail rows masked)
    if (stats) {
        #pragma unroll
        for (int ct = 0; ct < 4; ++ct) {
            float s1 = 0.f, s2 = 0.f;
            #pragma unroll
            for (int rt = 0; rt < 2; ++rt)
                #pragma unroll
                for (int r = 0; r < 4; ++r) {
                    int rowc = base + wid * 32 + rt * 16 + q * 4 + r;
                    float vv = (rowc < N) ? acc[rt][ct][r] : 0.f;
                    s1 += vv; s2 += vv * vv;
                }
            s1 += __shfl_xor(s1, 16); s2 += __shfl_xor(s2, 16);
            s1 += __shfl_xor(s1, 32); s2 += __shfl_xor(s2, 32);
            if (q == 0) {
                atomicAdd(&sred[ct * 16 + l15], s1);
                atomicAdd(&sred[64 + ct * 16 + l15], s2);
            }
        }
    }

    // epilogue: transpose through LDS -> coalesced stores
    #pragma unroll
    for (int rt = 0; rt < 2; ++rt)
        #pragma unroll
        for (int ct = 0; ct < 4; ++ct)
            #pragma unroll
            for (int r = 0; r < 4; ++r)
                sE[(wid * 32 + rt * 16 + q * 4 + r) * 68 + ct * 16 + l15] = acc[rt][ct][r];
    __syncthreads();
    if (stats && t < 64) {
        atomicAdd(&stats[t], sred[t]);
        atomicAdd(&stats[64 + t], sred[64 + t]);
    }

    int row = t >> 1, half = t & 1;
    int grow = base + row;
    if (grow < N) {
        const float* sp = sE + row * 68 + half * 32;
        if (outb) {
            unsigned short o[32];
            #pragma unroll
            for (int j = 0; j < 32; ++j) o[j] = f2bf(sp[j]);
            unsigned short* op = outb + ((size_t)grow << 6) + half * 32;
            ((uint4*)op)[0] = *(const uint4*)(o);
            ((uint4*)op)[1] = *(const uint4*)(o + 8);
            ((uint4*)op)[2] = *(const uint4*)(o + 16);
            ((uint4*)op)[3] = *(const uint4*)(o + 24);
        } else {
            const float* rp = resid + ((size_t)grow << 6) + half * 32;
            float* op = outf + ((size_t)grow << 6) + half * 32;
            #pragma unroll
            for (int j = 0; j < 8; ++j) {
                float4 v = *(const float4*)(sp + j * 4);
                float4 rv = *(const float4*)(rp + j * 4);
                v.x += rv.x; v.y += rv.y; v.z += rv.z; v.w += rv.w;
                *(float4*)(op + j * 4) = v;
            }
        }
    }
}

// ---------------------------------------------------------------------------
extern "C" void kernel_launch(void* const* d_in, const int* in_sizes, int n_in,
                              void* d_out, int out_size, void* d_ws, size_t ws_size,
                              hipStream_t stream) {
    const float* x      = (const float*)d_in[0];
    const int*   nbr    = (const int*)  d_in[1];
    const float* W1     = (const float*)d_in[2];
    const float* gamma1 = (const float*)d_in[3];
    const float* beta1  = (const float*)d_in[4];
    const float* W2     = (const float*)d_in[5];
    const float* gamma2 = (const float*)d_in[6];
    const float* beta2  = (const float*)d_in[7];
    float* out = (float*)d_out;

    int N = in_sizes[0] / 64;
    float invN = 1.0f / (float)N;

    char* ws = (char*)d_ws;
    float*          stats = (float*)ws;                           // 512 floats
    unsigned short* W1f   = (unsigned short*)(ws + 4096);         // 110592 bf16
    unsigned short* W2f   = W1f + 110592;
    unsigned short* hbuf  = W2f + 110592;                         // [N,64] bf16
    unsigned short* out1b = hbuf + (size_t)N * 64;                // [N,64] bf16

    int nb = (N + 127) / 128;

    hipMemsetAsync(stats, 0, 2048, stream);
    prep2<<<54 + 512, 256, 0, stream>>>(W1, W2, W1f, W2f, x, stats, N * 64);
    bn_relu_f32<<<768, 256, 0, stream>>>(x, stats, gamma1, beta1, hbuf, N * 16, invN);
    spconv<<<nb, 256, 0, stream>>>(hbuf, nbr, W1f, out1b, nullptr, nullptr, stats + 256, N);
    bn_relu_b16<<<768, 256, 0, stream>>>(out1b, stats + 256, gamma2, beta2, hbuf, N * 8, invN);
    spconv<<<nb, 256, 0, stream>>>(hbuf, nbr, W2f, nullptr, out, x, nullptr, N);
}

// Round 6
// 422.943 us; speedup vs baseline: 1.2900x; 1.0055x over previous
//
#include <hip/hip_runtime.h>

// ---------------------------------------------------------------------------
// ResNet sparse-conv block, round 6: R5 + conflict-free B ds_writes +
// LDS arena (epilogue aliases the B double-buffer) -> ~18KB LDS, 7-8 blocks/CU.
// ---------------------------------------------------------------------------

#define KOFF 27

typedef __bf16 bf16x8 __attribute__((ext_vector_type(8)));
typedef float floatx4 __attribute__((ext_vector_type(4)));

__device__ __forceinline__ unsigned short f2bf(float x) {
    union { float f; unsigned int u; } v; v.f = x;
    unsigned int u = v.u;
    unsigned int r = u + 0x7FFFu + ((u >> 16) & 1u);
    return (unsigned short)(r >> 16);
}
__device__ __forceinline__ float bf2f(unsigned short s) {
    union { float f; unsigned int u; } v; v.u = ((unsigned int)s) << 16; return v.f;
}

// --- prep: blocks 0..53 pack W (coalesced, LDS transpose); rest: x stats ----
// frag element j of (ct,ks) for lane (q,l15) = W[k][cin=ks*32+q*8+j][cout=ct*16+l15]
__global__ void prep2(const float* __restrict__ W1, const float* __restrict__ W2,
                      unsigned short* __restrict__ W1f, unsigned short* __restrict__ W2f,
                      const float* __restrict__ x, float* __restrict__ stats,
                      int total) {
    int b = blockIdx.x, t = threadIdx.x;
    if (b < 54) {
        __shared__ float sW[64 * 68];
        int k = b % 27;
        const float* src = (b < 27 ? W1 : W2) + k * 4096;
        unsigned short* dst = (b < 27 ? W1f : W2f) + (size_t)k * 4096;
        #pragma unroll
        for (int i = 0; i < 4; ++i) {
            int i4 = t + i * 256;
            float4 v = ((const float4*)src)[i4];
            int f = i4 * 4, r = f >> 6, c = f & 63;
            sW[r * 68 + c]     = v.x;
            sW[r * 68 + c + 1] = v.y;
            sW[r * 68 + c + 2] = v.z;
            sW[r * 68 + c + 3] = v.w;
        }
        __syncthreads();
        int fi = (t >> 5) & 7, ct = fi >> 1, ks = fi & 1;
        unsigned short o[16];
        #pragma unroll
        for (int d = 0; d < 2; ++d) {
            int lane2 = (t * 2 + d) & 63, q = lane2 >> 4, l15 = lane2 & 15;
            #pragma unroll
            for (int j = 0; j < 8; ++j) {
                int cin = ks * 32 + q * 8 + j, cout = ct * 16 + l15;
                o[d * 8 + j] = f2bf(sW[cin * 68 + cout]);
            }
        }
        ((uint4*)(dst + t * 16))[0] = *(const uint4*)(o);
        ((uint4*)(dst + t * 16))[1] = *(const uint4*)(o + 8);
        return;
    }
    __shared__ float s[128];
    if (t < 128) s[t] = 0.f;
    __syncthreads();
    int i = (b - 54) * 256 + t;
    int stride = (gridDim.x - 54) * 256;
    int c = i & 63;
    float s1 = 0.f, s2 = 0.f;
    for (; i < total; i += stride) { float v = x[i]; s1 += v; s2 += v * v; }
    atomicAdd(&s[c], s1);
    atomicAdd(&s[64 + c], s2);
    __syncthreads();
    if (t < 64) { atomicAdd(&stats[t], s[t]); atomicAdd(&stats[64 + t], s[64 + t]); }
}

// --- BN + ReLU + bf16 cast, fp32 input --------------------------------------
__global__ void bn_relu_f32(const float* __restrict__ in, const float* __restrict__ sums,
                            const float* __restrict__ gamma, const float* __restrict__ beta,
                            unsigned short* __restrict__ out, int total4, float invN) {
    __shared__ float sab[128];
    int t = threadIdx.x;
    if (t < 64) {
        float mu  = sums[t] * invN;
        float var = fmaxf(sums[64 + t] * invN - mu * mu, 0.f);
        float a   = gamma[t] * rsqrtf(var + 1e-5f);
        sab[t] = a; sab[64 + t] = beta[t] - mu * a;
    }
    __syncthreads();
    int i = blockIdx.x * blockDim.x + t;
    int stride = gridDim.x * blockDim.x;
    for (; i < total4; i += stride) {
        float4 v = ((const float4*)in)[i];
        int c0 = (i << 2) & 63;
        ushort4 o;
        o.x = f2bf(fmaxf(sab[c0]     * v.x + sab[64 + c0],     0.f));
        o.y = f2bf(fmaxf(sab[c0 + 1] * v.y + sab[64 + c0 + 1], 0.f));
        o.z = f2bf(fmaxf(sab[c0 + 2] * v.z + sab[64 + c0 + 2], 0.f));
        o.w = f2bf(fmaxf(sab[c0 + 3] * v.w + sab[64 + c0 + 3], 0.f));
        ((ushort4*)out)[i] = o;
    }
}

// --- BN + ReLU + bf16 cast, bf16 input --------------------------------------
__global__ void bn_relu_b16(const unsigned short* __restrict__ in, const float* __restrict__ sums,
                            const float* __restrict__ gamma, const float* __restrict__ beta,
                            unsigned short* __restrict__ out, int total8, float invN) {
    __shared__ float sab[128];
    int t = threadIdx.x;
    if (t < 64) {
        float mu  = sums[t] * invN;
        float var = fmaxf(sums[64 + t] * invN - mu * mu, 0.f);
        float a   = gamma[t] * rsqrtf(var + 1e-5f);
        sab[t] = a; sab[64 + t] = beta[t] - mu * a;
    }
    __syncthreads();
    int i = blockIdx.x * blockDim.x + t;
    int stride = gridDim.x * blockDim.x;
    for (; i < total8; i += stride) {
        uint4 v = ((const uint4*)in)[i];
        int c0 = (i << 3) & 63;
        unsigned int w[4] = {v.x, v.y, v.z, v.w};
        unsigned int o[4];
        #pragma unroll
        for (int p = 0; p < 4; ++p) {
            float f0 = bf2f((unsigned short)(w[p] & 0xffff));
            float f1 = bf2f((unsigned short)(w[p] >> 16));
            int c = c0 + p * 2;
            unsigned short r0 = f2bf(fmaxf(sab[c]     * f0 + sab[64 + c],     0.f));
            unsigned short r1 = f2bf(fmaxf(sab[c + 1] * f1 + sab[64 + c + 1], 0.f));
            o[p] = (unsigned int)r0 | ((unsigned int)r1 << 16);
        }
        ((uint4*)out)[i] = make_uint4(o[0], o[1], o[2], o[3]);
    }
}

#define MFMA(a, b, c) __builtin_amdgcn_mfma_f32_16x16x32_bf16(a, b, c, 0, 0, 0)
// lgkmcnt(0), vmcnt=no-wait(63), expcnt=no-wait(7)
#define WAIT_LGKM0() __builtin_amdgcn_s_waitcnt(0xC07F)

// --- LDS-shared-B gather->register MFMA sparse conv -------------------------
// Block 256 thr (4 waves), 128 output rows; wave owns two 16-row m-tiles.
// Per k: block stages the 8KB B-set once (lane-contiguous uint4 ds_writes,
// conflict-free); A-frags gathered 2 iters ahead into a 3-deep reg buffer.
// Raw s_barrier + lgkmcnt(0) only -> A/B prefetches stay in flight.
// Epilogue transpose buffer ALIASES the B double-buffer (arena) -> ~18KB LDS.
__global__ __launch_bounds__(256, 4) void spconv(
        const unsigned short* __restrict__ h,     // [N,64] bf16
        const int* __restrict__ idx,              // [N,27]
        const unsigned short* __restrict__ Wf,    // packed frags [27][8][64][8]
        unsigned short* __restrict__ outb,        // conv1 out (bf16) or null
        float* __restrict__ outf,                 // conv2 out (fp32) or null
        const float* __restrict__ resid,          // conv2 residual or null
        float* __restrict__ stats,                // conv1 fused stats or null
        int N) {
    __shared__ float4 arena[1088];                // 17408 B: sB[2][8KB] | sE 64x68 f32
    __shared__ float sred[128];
    unsigned short* sBb = (unsigned short*)arena; // sB[buf] = sBb + buf*4096
    float* sE = (float*)arena;

    int t = threadIdx.x, lane = t & 63, wid = t >> 6;
    int q = lane >> 4, l15 = lane & 15;
    int base = blockIdx.x * 128;
    if (t < 128) sred[t] = 0.f;

    int r0 = base + wid * 32 + l15;
    int r1 = r0 + 16;
    const int* ip0 = idx + (size_t)min(r0, N - 1) * KOFF;
    const int* ip1 = idx + (size_t)min(r1, N - 1) * KOFF;
    int qo = q * 8;

    floatx4 acc[2][4];
    #pragma unroll
    for (int a_ = 0; a_ < 2; ++a_)
        #pragma unroll
        for (int b_ = 0; b_ < 4; ++b_)
            acc[a_][b_] = floatx4{0.f, 0.f, 0.f, 0.f};

    // ---- prologue: A(0), A(1) gathers; B(0) staged+written; B(1) staged ----
    bf16x8 A0[4], A1[4], A2[4];
    {
        int g0 = ip0[0], g1 = ip1[0];
        const unsigned short* p0 = h + ((size_t)g0 << 6) + qo;
        const unsigned short* p1 = h + ((size_t)g1 << 6) + qo;
        A0[0] = *(const bf16x8*)p0; A0[1] = *(const bf16x8*)(p0 + 32);
        A0[2] = *(const bf16x8*)p1; A0[3] = *(const bf16x8*)(p1 + 32);
        g0 = ip0[1]; g1 = ip1[1];
        p0 = h + ((size_t)g0 << 6) + qo;
        p1 = h + ((size_t)g1 << 6) + qo;
        A1[0] = *(const bf16x8*)p0; A1[1] = *(const bf16x8*)(p0 + 32);
        A1[2] = *(const bf16x8*)p1; A1[3] = *(const bf16x8*)(p1 + 32);
    }
    int gc0 = ip0[2], gc1 = ip1[2];

    const uint4* Wf4 = (const uint4*)Wf;          // 8 shorts per uint4
    int so = wid * 64 + lane;                     // lane-contiguous slot
    uint4 bs0 = Wf4[so], bs1 = Wf4[256 + so];     // B(0)
    ((uint4*)sBb)[so] = bs0; ((uint4*)sBb)[256 + so] = bs1;
    bs0 = Wf4[512 + so]; bs1 = Wf4[512 + 256 + so];   // B(1) staged in regs

#define COMPUTE(ACUR, CB) {                                                    \
    const bf16x8* bp = (const bf16x8*)(sBb + (CB) * 4096);                     \
    bf16x8 f0 = bp[lane], f1 = bp[64 + lane], f2 = bp[128 + lane], f3 = bp[192 + lane]; \
    acc[0][0] = MFMA(ACUR[0], f0, acc[0][0]); acc[0][0] = MFMA(ACUR[1], f1, acc[0][0]); \
    acc[0][1] = MFMA(ACUR[0], f2, acc[0][1]); acc[0][1] = MFMA(ACUR[1], f3, acc[0][1]); \
    acc[1][0] = MFMA(ACUR[2], f0, acc[1][0]); acc[1][0] = MFMA(ACUR[3], f1, acc[1][0]); \
    acc[1][1] = MFMA(ACUR[2], f2, acc[1][1]); acc[1][1] = MFMA(ACUR[3], f3, acc[1][1]); \
    f0 = bp[256 + lane]; f1 = bp[320 + lane]; f2 = bp[384 + lane]; f3 = bp[448 + lane]; \
    acc[0][2] = MFMA(ACUR[0], f0, acc[0][2]); acc[0][2] = MFMA(ACUR[1], f1, acc[0][2]); \
    acc[0][3] = MFMA(ACUR[0], f2, acc[0][3]); acc[0][3] = MFMA(ACUR[1], f3, acc[0][3]); \
    acc[1][2] = MFMA(ACUR[2], f0, acc[1][2]); acc[1][2] = MFMA(ACUR[3], f1, acc[1][2]); \
    acc[1][3] = MFMA(ACUR[2], f2, acc[1][3]); acc[1][3] = MFMA(ACUR[3], f3, acc[1][3]); \
}

#define BODY_FULL(ACUR, ALD, KRT, CB, NB) {                                    \
    WAIT_LGKM0();                                                              \
    __builtin_amdgcn_s_barrier();                                              \
    ((uint4*)sBb)[(NB) * 512 + so] = bs0;                                      \
    ((uint4*)sBb)[(NB) * 512 + 256 + so] = bs1;                                \
    bs0 = Wf4[((KRT) + 2) * 512 + so]; bs1 = Wf4[((KRT) + 2) * 512 + 256 + so];\
    {                                                                          \
        const unsigned short* p0 = h + ((size_t)gc0 << 6) + qo;                \
        const unsigned short* p1 = h + ((size_t)gc1 << 6) + qo;                \
        ALD[0] = *(const bf16x8*)p0; ALD[1] = *(const bf16x8*)(p0 + 32);       \
        ALD[2] = *(const bf16x8*)p1; ALD[3] = *(const bf16x8*)(p1 + 32);       \
    }                                                                          \
    gc0 = ip0[(KRT) + 3]; gc1 = ip1[(KRT) + 3];                                \
    COMPUTE(ACUR, CB)                                                          \
}

    #pragma unroll 1
    for (int kk = 0; kk < 24; kk += 6) {
        BODY_FULL(A0, A2, kk + 0, 0, 1)
        BODY_FULL(A1, A0, kk + 1, 1, 0)
        BODY_FULL(A2, A1, kk + 2, 0, 1)
        BODY_FULL(A0, A2, kk + 3, 1, 0)
        BODY_FULL(A1, A0, kk + 4, 0, 1)
        BODY_FULL(A2, A1, kk + 5, 1, 0)
    }
    // k = 24: write B(25), stage B(26), gather A(26)
    {
        WAIT_LGKM0();
        __builtin_amdgcn_s_barrier();
        ((uint4*)sBb)[512 + so] = bs0; ((uint4*)sBb)[512 + 256 + so] = bs1;
        bs0 = Wf4[26 * 512 + so]; bs1 = Wf4[26 * 512 + 256 + so];
        {
            const unsigned short* p0 = h + ((size_t)gc0 << 6) + qo;
            const unsigned short* p1 = h + ((size_t)gc1 << 6) + qo;
            A2[0] = *(const bf16x8*)p0; A2[1] = *(const bf16x8*)(p0 + 32);
            A2[2] = *(const bf16x8*)p1; A2[3] = *(const bf16x8*)(p1 + 32);
        }
        COMPUTE(A0, 0)
    }
    // k = 25: write B(26)
    {
        WAIT_LGKM0();
        __builtin_amdgcn_s_barrier();
        ((uint4*)sBb)[so] = bs0; ((uint4*)sBb)[256 + so] = bs1;
        COMPUTE(A1, 1)
    }
    // k = 26
    {
        WAIT_LGKM0();
        __builtin_amdgcn_s_barrier();
        COMPUTE(A2, 0)
    }
#undef BODY_FULL
#undef COMPUTE

    // fused per-channel stats of conv1 output (tail rows masked)
    if (stats) {
        #pragma unroll
        for (int ct = 0; ct < 4; ++ct) {
            float s1 = 0.f, s2 = 0.f;
            #pragma unroll
            for (int rt = 0; rt < 2; ++rt)
                #pragma unroll
                for (int r = 0; r < 4; ++r) {
                    int rowc = base + wid * 32 + rt * 16 + q * 4 + r;
                    float vv = (rowc < N) ? acc[rt][ct][r] : 0.f;
                    s1 += vv; s2 += vv * vv;
                }
            s1 += __shfl_xor(s1, 16); s2 += __shfl_xor(s2, 16);
            s1 += __shfl_xor(s1, 32); s2 += __shfl_xor(s2, 32);
            if (q == 0) {
                atomicAdd(&sred[ct * 16 + l15], s1);
                atomicAdd(&sred[64 + ct * 16 + l15], s2);
            }
        }
    }

    __syncthreads();   // all sB reads done before sE (alias) is written

    // epilogue: two 64-row halves through the arena (aliases sB)
    #pragma unroll
    for (int hf = 0; hf < 2; ++hf) {
        if ((wid >> 1) == hf) {
            int lrow0 = (wid & 1) * 32;
            #pragma unroll
            for (int rt = 0; rt < 2; ++rt)
                #pragma unroll
                for (int ct = 0; ct < 4; ++ct)
                    #pragma unroll
                    for (int r = 0; r < 4; ++r)
                        sE[(lrow0 + rt * 16 + q * 4 + r) * 68 + ct * 16 + l15] = acc[rt][ct][r];
        }
        __syncthreads();
        if (hf == 0 && stats && t < 64) {
            atomicAdd(&stats[t], sred[t]);
            atomicAdd(&stats[64 + t], sred[64 + t]);
        }
        int rr = t >> 2, cc = t & 3;
        int grow = base + hf * 64 + rr;
        if (grow < N) {
            const float* sp = sE + rr * 68 + cc * 16;
            if (outb) {
                unsigned short o[16];
                #pragma unroll
                for (int j = 0; j < 16; ++j) o[j] = f2bf(sp[j]);
                unsigned short* op = outb + ((size_t)grow << 6) + cc * 16;
                ((uint4*)op)[0] = *(const uint4*)(o);
                ((uint4*)op)[1] = *(const uint4*)(o + 8);
            } else {
                const float* rp = resid + ((size_t)grow << 6) + cc * 16;
                float* op = outf + ((size_t)grow << 6) + cc * 16;
                #pragma unroll
                for (int j = 0; j < 4; ++j) {
                    float4 v = *(const float4*)(sp + j * 4);
                    float4 rv = *(const float4*)(rp + j * 4);
                    v.x += rv.x; v.y += rv.y; v.z += rv.z; v.w += rv.w;
                    *(float4*)(op + j * 4) = v;
                }
            }
        }
        if (hf == 0) __syncthreads();
    }
}

// ---------------------------------------------------------------------------
extern "C" void kernel_launch(void* const* d_in, const int* in_sizes, int n_in,
                              void* d_out, int out_size, void* d_ws, size_t ws_size,
                              hipStream_t stream) {
    const float* x      = (const float*)d_in[0];
    const int*   nbr    = (const int*)  d_in[1];
    const float* W1     = (const float*)d_in[2];
    const float* gamma1 = (const float*)d_in[3];
    const float* beta1  = (const float*)d_in[4];
    const float* W2     = (const float*)d_in[5];
    const float* gamma2 = (const float*)d_in[6];
    const float* beta2  = (const float*)d_in[7];
    float* out = (float*)d_out;

    int N = in_sizes[0] / 64;
    float invN = 1.0f / (float)N;

    char* ws = (char*)d_ws;
    float*          stats = (float*)ws;                           // 512 floats
    unsigned short* W1f   = (unsigned short*)(ws + 4096);         // 110592 bf16
    unsigned short* W2f   = W1f + 110592;
    unsigned short* hbuf  = W2f + 110592;                         // [N,64] bf16
    unsigned short* out1b = hbuf + (size_t)N * 64;                // [N,64] bf16

    int nb = (N + 127) / 128;

    hipMemsetAsync(stats, 0, 2048, stream);
    prep2<<<54 + 512, 256, 0, stream>>>(W1, W2, W1f, W2f, x, stats, N * 64);
    bn_relu_f32<<<768, 256, 0, stream>>>(x, stats, gamma1, beta1, hbuf, N * 16, invN);
    spconv<<<nb, 256, 0, stream>>>(hbuf, nbr, W1f, out1b, nullptr, nullptr, stats + 256, N);
    bn_relu_b16<<<768, 256, 0, stream>>>(out1b, stats + 256, gamma2, beta2, hbuf, N * 8, invN);
    spconv<<<nb, 256, 0, stream>>>(hbuf, nbr, W2f, nullptr, out, x, nullptr, N);
}